// Round 8
// baseline (722.458 us; speedup 1.0000x reference)
//
#include <hip/hip_runtime.h>
#include <hip/hip_bf16.h>

typedef unsigned int uint32;
typedef unsigned short ushort16;
typedef __attribute__((ext_vector_type(8))) __bf16 bf16x8;
typedef __attribute__((ext_vector_type(4))) float f32x4;

__device__ __forceinline__ ushort16 f2bf(float f) {
    uint32 u = __float_as_uint(f);
    u += 0x7fff + ((u >> 16) & 1);       // round-to-nearest-even
    return (ushort16)(u >> 16);
}
// pack two fp32 -> dword of 2 bf16 (a in low half)
__device__ __forceinline__ uint32 pack2rn(float a, float b) {
    uint32 ua = __float_as_uint(a) + 0x8000u;
    uint32 ub = __float_as_uint(b) + 0x8000u;
    return __builtin_amdgcn_perm(ub, ua, 0x07060302);  // [a.hi16, b.hi16]
}
__device__ __forceinline__ float blo(uint32 u) { return __uint_as_float(u << 16); }
__device__ __forceinline__ float bhi(uint32 u) { return __uint_as_float(u & 0xffff0000u); }

__device__ __forceinline__ void storeC(float v, float* p) { *p = v; }
__device__ __forceinline__ void storeC(float v, ushort16* p) { *p = f2bf(v); }

// async 16B global -> LDS (linear dest: wave-uniform base + lane*16)
__device__ __forceinline__ void gload_lds16(const void* g, void* l) {
    __builtin_amdgcn_global_load_lds(
        (const __attribute__((address_space(1))) unsigned int*)g,
        (__attribute__((address_space(3))) unsigned int*)l, 16, 0, 0);
}

// 16-lane reductions on the VALU pipe via DPP row_ror (NOT ds_bpermute):
// row_ror:n ctrl = 0x120 + n
#define DPP_ROR(v, n)                                                        \
    __uint_as_float(__builtin_amdgcn_update_dpp(                             \
        (int)__float_as_uint(v), (int)__float_as_uint(v), 0x120 + (n),       \
        0xf, 0xf, false))
__device__ __forceinline__ float rowmax16(float v) {
    v = fmaxf(v, DPP_ROR(v, 8));
    v = fmaxf(v, DPP_ROR(v, 4));
    v = fmaxf(v, DPP_ROR(v, 2));
    v = fmaxf(v, DPP_ROR(v, 1));
    return v;
}
__device__ __forceinline__ float rowsum16(float v) {
    v += DPP_ROR(v, 8);
    v += DPP_ROR(v, 4);
    v += DPP_ROR(v, 2);
    v += DPP_ROR(v, 1);
    return v;
}

// -log2(5000)/64 : rope inv-freq exponent step
#define ROPE_NEGSTEP (-0.19199550593046019f)

// rope a fp32 pair (tr,ti) at pair-index ip, seq pos s; scale; pack to 2 bf16
__device__ __forceinline__ uint32 rope_pack(float tr, float ti, int ip, int s,
                                            float sc) {
    float inv = exp2f((float)ip * ROPE_NEGSTEP);
    float ang = (float)s * inv;
    float sn = __sinf(ang), cs = __cosf(ang);
    return pack2rn((tr * cs - ti * sn) * sc, (tr * sn + ti * cs) * sc);
}

// ---------------------------------------------------------------------------
// Prep (one launch): blocks [0,8192) convert x,y fp32->bf16;
// blocks [8192,18432) transpose Wq/Wk/Wv/Wo [4096][N] fp32 -> [N][4096] bf16.
// ---------------------------------------------------------------------------
__global__ __launch_bounds__(256) void prep_kernel(
    const float* __restrict__ x, const float* __restrict__ y,
    const float* __restrict__ Wq, const float* __restrict__ Wk,
    const float* __restrict__ Wv, const float* __restrict__ Wo,
    ushort16* __restrict__ xb, ushort16* __restrict__ yb,
    ushort16* __restrict__ Wqt, ushort16* __restrict__ Wkvt,
    ushort16* __restrict__ Wot)
{
    __shared__ float tile[64][65];
    const int b = blockIdx.x;
    if (b < 8192) {                       // conv: 2*n8 threads, n8 = S*D/8
        const int n8 = 1048576;
        int idx = b * 256 + threadIdx.x;
        const float* S = (idx < n8) ? x : y;
        ushort16*    D = (idx < n8) ? xb : yb;
        int i = (idx < n8) ? idx : idx - n8;
        float4 a = ((const float4*)S)[2 * i];
        float4 c = ((const float4*)S)[2 * i + 1];
        uint4 u;
        u.x = pack2rn(a.x, a.y); u.y = pack2rn(a.z, a.w);
        u.z = pack2rn(c.x, c.y); u.w = pack2rn(c.z, c.w);
        ((uint4*)D)[i] = u;
        return;
    }
    int t = b - 8192;                     // 0..10239
    int kblk = t & 63, sel = t >> 6;      // sel 0..159
    const float* W; ushort16* Wt; int N, n0;
    if (sel < 64)      { W = Wq; Wt = Wqt;  N = 4096; n0 = sel * 64; }
    else if (sel < 80) { W = Wk; Wt = Wkvt; N = 1024; n0 = (sel - 64) * 64; }
    else if (sel < 96) { W = Wv; Wt = Wkvt + (size_t)1024 * 4096; N = 1024; n0 = (sel - 80) * 64; }
    else               { W = Wo; Wt = Wot;  N = 4096; n0 = (sel - 96) * 64; }
    const int k0 = kblk * 64;
#pragma unroll
    for (int it = 0; it < 16; ++it) {
        int idx = threadIdx.x + it * 256;
        int r = idx >> 6, c = idx & 63;
        tile[r][c] = W[(size_t)(k0 + r) * N + n0 + c];
    }
    __syncthreads();
#pragma unroll
    for (int it = 0; it < 8; ++it) {
        int idx = threadIdx.x + it * 256;
        int nr = idx >> 5, kp = idx & 31;
        uint32 u = pack2rn(tile[2 * kp][nr], tile[2 * kp + 1][nr]);
        *(uint32*)&Wt[(size_t)(n0 + nr) * 4096 + k0 + 2 * kp] = u;
    }
}

// ---------------------------------------------------------------------------
// Merged Q + KV GEMM (grid 48 x 16), m97 structure, plain epilogue.
//   x < 32 : Q  = xb @ Wqt^T + bq  -> fp32 Q [2048][4096] (in d_out)
//   x >= 32: KV = yb @ Wkvt^T + bk|bv -> bf16 KVb [2048][2048]
// ---------------------------------------------------------------------------
__global__ __launch_bounds__(256) void gemm_qkv(
    const ushort16* __restrict__ xb, const ushort16* __restrict__ yb,
    const ushort16* __restrict__ Wqt, const ushort16* __restrict__ Wkvt,
    const float* __restrict__ bq, const float* __restrict__ bk,
    const float* __restrict__ bv, float* __restrict__ Q,
    ushort16* __restrict__ KVb)
{
    __shared__ __align__(16) ushort16 As[128 * 64];
    __shared__ __align__(16) ushort16 Bs[128 * 64];

    const bool isQ = (blockIdx.x < 32);
    const ushort16* A = isQ ? xb : yb;
    const ushort16* B = isQ ? Wqt : Wkvt;
    const int gn0 = (isQ ? (int)blockIdx.x : (int)blockIdx.x - 32) * 128;
    const int gm0 = blockIdx.y * 128;
    const int K = 4096;

    const int tid  = threadIdx.x;
    const int lane = tid & 63, wave = tid >> 6;
    const int quad = lane >> 4, m16 = lane & 15;
    const int wm = (wave >> 1) * 64, wn = (wave & 1) * 64;

    f32x4 acc[4][4];
#pragma unroll
    for (int i = 0; i < 4; ++i)
#pragma unroll
        for (int j = 0; j < 4; ++j) acc[i][j] = (f32x4){0.f, 0.f, 0.f, 0.f};

    const int rl = lane >> 3, cl = lane & 7;
    const int clog = cl ^ (rl & 7);
    const ushort16* Ag = A + (size_t)(gm0 + wave * 32 + rl) * K + clog * 8;
    const ushort16* Bg = B + (size_t)(gn0 + wave * 32 + rl) * K + clog * 8;
    char* AsW = (char*)As + wave * 4096;
    char* BsW = (char*)Bs + wave * 4096;

    for (int k0 = 0; k0 < K; k0 += 64) {
        __syncthreads();
#pragma unroll
        for (int i = 0; i < 4; ++i) {
            gload_lds16(Ag + (size_t)(8 * i) * K, AsW + i * 1024);
            gload_lds16(Bg + (size_t)(8 * i) * K, BsW + i * 1024);
        }
        Ag += 64; Bg += 64;
        __syncthreads();

#pragma unroll
        for (int s = 0; s < 2; ++s) {
            bf16x8 aF[4], bF[4];
            const int cr = s * 4 + quad;
#pragma unroll
            for (int i = 0; i < 4; ++i) {
                int r = wm + i * 16 + m16;
                aF[i] = *(const bf16x8*)&As[r * 64 + ((cr ^ (r & 7)) * 8)];
                int n = wn + i * 16 + m16;
                bF[i] = *(const bf16x8*)&Bs[n * 64 + ((cr ^ (n & 7)) * 8)];
            }
            __builtin_amdgcn_s_setprio(1);
#pragma unroll
            for (int i = 0; i < 4; ++i)
#pragma unroll
                for (int j = 0; j < 4; ++j)
                    acc[i][j] = __builtin_amdgcn_mfma_f32_16x16x32_bf16(
                        aF[i], bF[j], acc[i][j], 0, 0, 0);
            __builtin_amdgcn_s_setprio(0);
        }
    }

#pragma unroll
    for (int j = 0; j < 4; ++j) {
        int col = gn0 + wn + j * 16 + m16;
        float bb = isQ ? bq[col] : ((col < 1024) ? bk[col] : bv[col - 1024]);
#pragma unroll
        for (int i = 0; i < 4; ++i) {
            int row0 = gm0 + wm + i * 16 + quad * 4;
#pragma unroll
            for (int r = 0; r < 4; ++r) {
                float v = acc[i][j][r] + bb;
                if (isQ) Q[(size_t)(row0 + r) * 4096 + col] = v;
                else     KVb[(size_t)(row0 + r) * 2048 + col] = f2bf(v);
            }
        }
    }
}

// ---------------------------------------------------------------------------
// MFMA GEMM (m97 structure): C = A[M,K] @ B[N,K]^T + bias (out projection).
// ---------------------------------------------------------------------------
template <typename OutT>
__global__ __launch_bounds__(256) void gemm_mfma(
    const ushort16* __restrict__ A, const ushort16* __restrict__ B,
    const float* __restrict__ b1, OutT* __restrict__ C, int N, int K)
{
    __shared__ __align__(16) ushort16 As[128 * 64];
    __shared__ __align__(16) ushort16 Bs[128 * 64];

    const int tid  = threadIdx.x;
    const int lane = tid & 63, wave = tid >> 6;
    const int quad = lane >> 4, m16 = lane & 15;
    const int wm = (wave >> 1) * 64, wn = (wave & 1) * 64;
    const int gm0 = blockIdx.y * 128, gn0 = blockIdx.x * 128;

    f32x4 acc[4][4];
#pragma unroll
    for (int i = 0; i < 4; ++i)
#pragma unroll
        for (int j = 0; j < 4; ++j) acc[i][j] = (f32x4){0.f, 0.f, 0.f, 0.f};

    const int rl = lane >> 3, cl = lane & 7;
    const int clog = cl ^ (rl & 7);
    const ushort16* Ag = A + (size_t)(gm0 + wave * 32 + rl) * K + clog * 8;
    const ushort16* Bg = B + (size_t)(gn0 + wave * 32 + rl) * K + clog * 8;
    char* AsW = (char*)As + wave * 4096;
    char* BsW = (char*)Bs + wave * 4096;

    for (int k0 = 0; k0 < K; k0 += 64) {
        __syncthreads();
#pragma unroll
        for (int i = 0; i < 4; ++i) {
            gload_lds16(Ag + (size_t)(8 * i) * K, AsW + i * 1024);
            gload_lds16(Bg + (size_t)(8 * i) * K, BsW + i * 1024);
        }
        Ag += 64; Bg += 64;
        __syncthreads();

#pragma unroll
        for (int s = 0; s < 2; ++s) {
            bf16x8 aF[4], bF[4];
            const int cr = s * 4 + quad;
#pragma unroll
            for (int i = 0; i < 4; ++i) {
                int r = wm + i * 16 + m16;
                aF[i] = *(const bf16x8*)&As[r * 64 + ((cr ^ (r & 7)) * 8)];
                int n = wn + i * 16 + m16;
                bF[i] = *(const bf16x8*)&Bs[n * 64 + ((cr ^ (n & 7)) * 8)];
            }
            __builtin_amdgcn_s_setprio(1);
#pragma unroll
            for (int i = 0; i < 4; ++i)
#pragma unroll
                for (int j = 0; j < 4; ++j)
                    acc[i][j] = __builtin_amdgcn_mfma_f32_16x16x32_bf16(
                        aF[i], bF[j], acc[i][j], 0, 0, 0);
            __builtin_amdgcn_s_setprio(0);
        }
    }

#pragma unroll
    for (int j = 0; j < 4; ++j) {
        int col = gn0 + wn + j * 16 + m16;
        float bb = b1[col];
#pragma unroll
        for (int i = 0; i < 4; ++i) {
            int row0 = gm0 + wm + i * 16 + quad * 4;
#pragma unroll
            for (int r = 0; r < 4; ++r)
                storeC(acc[i][j][r] + bb, C + (size_t)(row0 + r) * N + col);
        }
    }
}

// ---------------------------------------------------------------------------
// Merged rope-K + V-transpose (one small launch):
//  blocks [0,4096): rope bf16 K in-place (KVb cols [0,1024))
//  blocks [4096,4608): transpose V (KVb cols [1024,2048)) -> Vt[1024][2048]
// ---------------------------------------------------------------------------
__global__ __launch_bounds__(256) void ropek_vt_kernel(
    ushort16* __restrict__ KVb, ushort16* __restrict__ Vt)
{
    __shared__ ushort16 tile[64][66];
    const int b = blockIdx.x;
    if (b < 4096) {                        // rope K in place
        int idx = b * 256 + threadIdx.x;
        int i   = idx & 63;
        int rem = idx >> 6;                // s*8 + h
        int s   = rem >> 3, h = rem & 7;
        float inv = exp2f((float)i * ROPE_NEGSTEP);
        float ang = (float)s * inv;
        float cs = __cosf(ang), sn = __sinf(ang);
        uint32* p = (uint32*)&KVb[(size_t)s * 2048 + h * 128 + 2 * i];
        uint32 u = *p;
        float tr = blo(u), ti = bhi(u);
        *p = pack2rn(tr * cs - ti * sn, tr * sn + ti * cs);
        return;
    }
    // V^T 64x64 tile
    int t = b - 4096;
    int s0 = (t >> 4) * 64, d0 = (t & 15) * 64;
#pragma unroll
    for (int it = 0; it < 2; ++it) {
        int i = threadIdx.x + it * 256;    // 0..511
        int r = i >> 3, c = (i & 7) * 8;
        *(uint4*)&tile[r][c] = *(const uint4*)&KVb[(size_t)(s0 + r) * 2048 + 1024 + d0 + c];
    }
    __syncthreads();
#pragma unroll
    for (int it = 0; it < 2; ++it) {
        int i = threadIdx.x + it * 256;
        int dr = i >> 3, sc = (i & 7) * 8;
        uint32 w[4];
#pragma unroll
        for (int q = 0; q < 4; ++q)
            w[q] = (uint32)tile[sc + 2 * q][dr] | ((uint32)tile[sc + 2 * q + 1][dr] << 16);
        *(uint4*)&Vt[(size_t)(d0 + dr) * 2048 + s0 + sc] = *(uint4*)w;
    }
}

// ---------------------------------------------------------------------------
// MFMA flash attention, DUAL-TILE: block x handles q-tiles A=31-x and B=x in
// ONE kv sweep. Each staged K/V tile serves both: every kb/vb LDS fragment
// read feeds TWO MFMAs while k0 <= q0B (LDS-pipe traffic per MFMA halves),
// and K/V staging DMA drops ~26%. Compute per block stays exactly 33
// unit-equivalents -> CU balance preserved. Softmax reductions use DPP
// row_ror (VALU pipe) instead of shfl/ds_bpermute (LDS pipe).
// Async dbuf K, DMA'd V from Vt, counted vmcnt before PV, defer-max,
// in-register rope-Q at fragment load.
// LDS: Kb 32K + Vs 16K + Ps 2x9K = 66 KB -> 2 blocks/CU. Grid 16 x 32.
// ---------------------------------------------------------------------------
__global__ __launch_bounds__(256) void flash_attn_kernel(
    const float* __restrict__ Qf, const ushort16* __restrict__ KVb,
    const ushort16* __restrict__ Vtg, ushort16* __restrict__ O)
{
    __shared__ __align__(16) ushort16 Kb[2][64 * 128];  // [kv][d], swizzled
    __shared__ __align__(16) ushort16 Vs[128 * 64];     // [d][kv], swizzled
    __shared__ __align__(16) ushort16 Ps[2][64 * 72];   // [q][kv], stride 72

    const int tid  = threadIdx.x;
    const int lane = tid & 63, wave = tid >> 6;
    const int quad = lane >> 4, m16 = lane & 15;
    const int h = (int)blockIdx.y, kvh = h >> 2;

    const ushort16* Kbase = KVb + kvh * 128;
    const ushort16* Vbase = Vtg + (size_t)(kvh * 128) * 2048;

    const int rK = lane >> 4;
    const ushort16* pKe = Kbase + (size_t)(wave * 16 + rK) * 2048
                        + (((lane & 15) ^ rK) * 8);
    const ushort16* pKo = Kbase + (size_t)(wave * 16 + 4 + rK) * 2048
                        + (((lane & 15) ^ (4 + rK)) * 8);
    const int rV = lane >> 3;
    const ushort16* pV  = Vbase + (size_t)(wave * 32 + rV) * 2048
                        + (((lane & 7) ^ rV) * 8);
    char* ldsK0 = (char*)&Kb[0][0] + wave * 4096;
    char* ldsK1 = (char*)&Kb[1][0] + wave * 4096;
    char* ldsV  = (char*)&Vs[0]    + wave * 4096;

#define STAGE_K(dst, kk) do {                                   \
        const ushort16* _s0 = pKe + (size_t)(kk) * 2048;        \
        const ushort16* _s1 = pKo + (size_t)(kk) * 2048;        \
        gload_lds16(_s0,            (dst));                     \
        gload_lds16(_s1,            (dst) + 1024);              \
        gload_lds16(_s0 + 8 * 2048, (dst) + 2048);              \
        gload_lds16(_s1 + 8 * 2048, (dst) + 3072);              \
    } while (0)
#define STAGE_V(kk) do {                                        \
        const ushort16* _sv = pV + (kk);                        \
        gload_lds16(_sv,             ldsV);                     \
        gload_lds16(_sv +  8 * 2048, ldsV + 1024);              \
        gload_lds16(_sv + 16 * 2048, ldsV + 2048);              \
        gload_lds16(_sv + 24 * 2048, ldsV + 3072);              \
    } while (0)

    const int q0A = (31 - (int)blockIdx.x) * 64;
    const int q0B = (int)blockIdx.x * 64;
    const float sc = 0.08838834764831845f * 1.4426950408889634f;

    // Q fragments for both tiles, rope applied in-register
    bf16x8 qaA[4], qaB[4];
    {
        const int rowA = q0A + wave * 16 + m16;
        const int rowB = q0B + wave * 16 + m16;
        const float* qpA = Qf + (size_t)rowA * 4096 + h * 128 + quad * 8;
        const float* qpB = Qf + (size_t)rowB * 4096 + h * 128 + quad * 8;
#pragma unroll
        for (int ks = 0; ks < 4; ++ks) {
            int ip0 = quad * 4 + ks * 16;
            float4 a = *(const float4*)(qpA + ks * 32);
            float4 b = *(const float4*)(qpA + ks * 32 + 4);
            uint4 u;
            u.x = rope_pack(a.x, a.y, ip0 + 0, rowA, sc);
            u.y = rope_pack(a.z, a.w, ip0 + 1, rowA, sc);
            u.z = rope_pack(b.x, b.y, ip0 + 2, rowA, sc);
            u.w = rope_pack(b.z, b.w, ip0 + 3, rowA, sc);
            qaA[ks] = *(bf16x8*)&u;
            a = *(const float4*)(qpB + ks * 32);
            b = *(const float4*)(qpB + ks * 32 + 4);
            u.x = rope_pack(a.x, a.y, ip0 + 0, rowB, sc);
            u.y = rope_pack(a.z, a.w, ip0 + 1, rowB, sc);
            u.z = rope_pack(b.x, b.y, ip0 + 2, rowB, sc);
            u.w = rope_pack(b.z, b.w, ip0 + 3, rowB, sc);
            qaB[ks] = *(bf16x8*)&u;
        }
    }

    f32x4 accA[8], accB[8];
#pragma unroll
    for (int t = 0; t < 8; ++t) {
        accA[t] = (f32x4){0.f, 0.f, 0.f, 0.f};
        accB[t] = (f32x4){0.f, 0.f, 0.f, 0.f};
    }
    float mA[4], lA[4], mB[4], lB[4];
#pragma unroll
    for (int r = 0; r < 4; ++r) {
        mA[r] = -1e30f; lA[r] = 0.f; mB[r] = -1e30f; lB[r] = 0.f;
    }

    int cur = 0;
    STAGE_K(ldsK0, 0);

    for (int k0 = 0; k0 <= q0A; k0 += 64) {
        __syncthreads();         // K(cur) landed; Vs reusable

        STAGE_V(k0);
        const bool pre = (k0 + 64 <= q0A);
        if (pre) STAGE_K(cur ? ldsK0 : ldsK1, k0 + 64);
        const bool doB = (k0 <= q0B);

        const ushort16* Kcur = &Kb[cur][0];

        // S = Q @ K^T for A (and B): each kb read feeds 2 MFMAs
        f32x4 sA[4], sB[4];
#pragma unroll
        for (int j = 0; j < 4; ++j) {
            sA[j] = (f32x4){0.f, 0.f, 0.f, 0.f};
            sB[j] = (f32x4){0.f, 0.f, 0.f, 0.f};
        }
        __builtin_amdgcn_s_setprio(1);
#pragma unroll
        for (int ks = 0; ks < 4; ++ks) {
#pragma unroll
            for (int j = 0; j < 4; ++j) {
                int n = j * 16 + m16;
                bf16x8 kb = *(const bf16x8*)&Kcur[n * 128 + (((ks * 4 + quad) ^ (n & 7)) * 8)];
                sA[j] = __builtin_amdgcn_mfma_f32_16x16x32_bf16(qaA[ks], kb, sA[j], 0, 0, 0);
                if (doB)
                    sB[j] = __builtin_amdgcn_mfma_f32_16x16x32_bf16(qaB[ks], kb, sB[j], 0, 0, 0);
            }
        }
        __builtin_amdgcn_s_setprio(0);

        // causal masks on each tile's diagonal
        if (k0 == q0A) {
            int qr = wave * 16 + quad * 4;
#pragma unroll
            for (int j = 0; j < 4; ++j) {
                int kvl = j * 16 + m16;
#pragma unroll
                for (int r = 0; r < 4; ++r)
                    if (kvl > qr + r) sA[j][r] = -1e30f;
            }
        }
        if (k0 == q0B) {
            int qr = wave * 16 + quad * 4;
#pragma unroll
            for (int j = 0; j < 4; ++j) {
                int kvl = j * 16 + m16;
#pragma unroll
                for (int r = 0; r < 4; ++r)
                    if (kvl > qr + r) sB[j][r] = -1e30f;
            }
        }

        // --- softmax A (exp2 domain, DPP reductions, defer-max) ---
        {
            float rm[4];
#pragma unroll
            for (int r = 0; r < 4; ++r)
                rm[r] = rowmax16(fmaxf(fmaxf(sA[0][r], sA[1][r]),
                                       fmaxf(sA[2][r], sA[3][r])));
            int ok = (rm[0] <= mA[0]) & (rm[1] <= mA[1]) &
                     (rm[2] <= mA[2]) & (rm[3] <= mA[3]);
            if (!__all(ok)) {
#pragma unroll
                for (int r = 0; r < 4; ++r) {
                    float mnew = fmaxf(mA[r], rm[r]);
                    float al = exp2f(mA[r] - mnew);
                    lA[r] *= al; mA[r] = mnew;
#pragma unroll
                    for (int t = 0; t < 8; ++t) accA[t][r] *= al;
                }
            }
#pragma unroll
            for (int r = 0; r < 4; ++r) {
                float rs = 0.f;
#pragma unroll
                for (int j = 0; j < 4; ++j) {
                    float pv = exp2f(sA[j][r] - mA[r]);
                    sA[j][r] = pv; rs += pv;
                }
                lA[r] += rowsum16(rs);
                int q = wave * 16 + quad * 4 + r;
#pragma unroll
                for (int j = 0; j < 4; ++j) {
                    int kv = j * 16 + m16;
                    Ps[0][q * 72 + (((kv >> 3) ^ (q & 7)) * 8) + (kv & 7)] = f2bf(sA[j][r]);
                }
            }
        }
        // --- softmax B ---
        if (doB) {
            float rm[4];
#pragma unroll
            for (int r = 0; r < 4; ++r)
                rm[r] = rowmax16(fmaxf(fmaxf(sB[0][r], sB[1][r]),
                                       fmaxf(sB[2][r], sB[3][r])));
            int ok = (rm[0] <= mB[0]) & (rm[1] <= mB[1]) &
                     (rm[2] <= mB[2]) & (rm[3] <= mB[3]);
            if (!__all(ok)) {
#pragma unroll
                for (int r = 0; r < 4; ++r) {
                    float mnew = fmaxf(mB[r], rm[r]);
                    float al = exp2f(mB[r] - mnew);
                    lB[r] *= al; mB[r] = mnew;
#pragma unroll
                    for (int t = 0; t < 8; ++t) accB[t][r] *= al;
                }
            }
#pragma unroll
            for (int r = 0; r < 4; ++r) {
                float rs = 0.f;
#pragma unroll
                for (int j = 0; j < 4; ++j) {
                    float pv = exp2f(sB[j][r] - mB[r]);
                    sB[j][r] = pv; rs += pv;
                }
                lB[r] += rowsum16(rs);
                int q = wave * 16 + quad * 4 + r;
#pragma unroll
                for (int j = 0; j < 4; ++j) {
                    int kv = j * 16 + m16;
                    Ps[1][q * 72 + (((kv >> 3) ^ (q & 7)) * 8) + (kv & 7)] = f2bf(sB[j][r]);
                }
            }
        }

        // drain own V loads (counted: K prefetch spans the barrier)
        if (pre) { asm volatile("s_waitcnt vmcnt(4)" ::: "memory"); }
        else     { asm volatile("s_waitcnt vmcnt(0)" ::: "memory"); }
        __builtin_amdgcn_sched_barrier(0);
        __builtin_amdgcn_s_barrier();

        // O += P @ V : each vb read feeds 2 MFMAs
        int qrow = wave * 16 + m16;
#pragma unroll
        for (int ks2 = 0; ks2 < 2; ++ks2) {
            bf16x8 paA = *(const bf16x8*)&Ps[0][qrow * 72 + (((ks2 * 4 + quad) ^ (qrow & 7)) * 8)];
            bf16x8 paB;
            if (doB)
                paB = *(const bf16x8*)&Ps[1][qrow * 72 + (((ks2 * 4 + quad) ^ (qrow & 7)) * 8)];
            __builtin_amdgcn_s_setprio(1);
#pragma unroll
            for (int t = 0; t < 8; ++t) {
                int d = t * 16 + m16;
                bf16x8 vb = *(const bf16x8*)&Vs[d * 64 + (((ks2 * 4 + quad) ^ (d & 7)) * 8)];
                accA[t] = __builtin_amdgcn_mfma_f32_16x16x32_bf16(paA, vb, accA[t], 0, 0, 0);
                if (doB)
                    accB[t] = __builtin_amdgcn_mfma_f32_16x16x32_bf16(paB, vb, accB[t], 0, 0, 0);
            }
            __builtin_amdgcn_s_setprio(0);
        }
        cur ^= 1;
    }

    // epilogue: O = bf16(acc/l) for both tiles
    {
        ushort16* op = O + (size_t)(q0A + wave * 16 + quad * 4) * 4096 + h * 128 + m16;
#pragma unroll
        for (int r = 0; r < 4; ++r) {
            float inv = 1.0f / lA[r];
#pragma unroll
            for (int t = 0; t < 8; ++t)
                op[(size_t)r * 4096 + t * 16] = f2bf(accA[t][r] * inv);
        }
        op = O + (size_t)(q0B + wave * 16 + quad * 4) * 4096 + h * 128 + m16;
#pragma unroll
        for (int r = 0; r < 4; ++r) {
            float inv = 1.0f / lB[r];
#pragma unroll
            for (int t = 0; t < 8; ++t)
                op[(size_t)r * 4096 + t * 16] = f2bf(accB[t][r] * inv);
        }
    }
#undef STAGE_K
#undef STAGE_V
}

// ---------------------------------------------------------------------------
extern "C" void kernel_launch(void* const* d_in, const int* in_sizes, int n_in,
                              void* d_out, int out_size, void* d_ws, size_t ws_size,
                              hipStream_t stream)
{
    const float* x  = (const float*)d_in[0];
    const float* y  = (const float*)d_in[1];
    const float* Wq = (const float*)d_in[2];
    const float* bq = (const float*)d_in[3];
    const float* Wk = (const float*)d_in[4];
    const float* bk = (const float*)d_in[5];
    const float* Wv = (const float*)d_in[6];
    const float* bv = (const float*)d_in[7];
    const float* Wo = (const float*)d_in[8];
    const float* bo = (const float*)d_in[9];
    float* out = (float*)d_out;

    const size_t MB = 1024 * 1024;

    // workspace layout (124 MB):
    char* ws = (char*)d_ws;
    ushort16* xb   = (ushort16*)(ws);             // 16 MB
    ushort16* yb   = (ushort16*)(ws + 16 * MB);   // 16 MB, reused as Ao
    ushort16* Wqt  = (ushort16*)(ws + 32 * MB);   // 32 MB [4096][4096]
    ushort16* Wkvt = (ushort16*)(ws + 64 * MB);   // 16 MB [2048][4096]
    ushort16* Wot  = (ushort16*)(ws + 80 * MB);   // 32 MB [4096][4096]
    ushort16* KVb  = (ushort16*)(ws + 112 * MB);  //  8 MB [S][2048] = K|V
    ushort16* Vtg  = (ushort16*)(ws + 120 * MB);  //  4 MB [1024][2048] = V^T
    ushort16* Ao   = yb;                          // alias (yb dead after QKV)
    float*    Q    = out;                         // fp32 Q in d_out (32 MB),
                                                  // dead before out-GEMM write

    prep_kernel<<<18432, 256, 0, stream>>>(x, y, Wq, Wk, Wv, Wo,
                                           xb, yb, Wqt, Wkvt, Wot);

    // Q = x@Wq+bq (fp32), KV = y@[Wk|Wv]+[bk|bv] (bf16), one launch
    gemm_qkv<<<dim3(48, 16), 256, 0, stream>>>(
        xb, yb, Wqt, Wkvt, bq, bk, bv, Q, KVb);

    // rope K in place + V -> V^T
    ropek_vt_kernel<<<4608, 256, 0, stream>>>(KVb, Vtg);

    // dual-tile flash: reads fp32 Q, ropes in-register
    flash_attn_kernel<<<dim3(16, 32), 256, 0, stream>>>(Q, KVb, Vtg, Ao);

    gemm_mfma<float><<<dim3(32, 16), 256, 0, stream>>>(
        Ao, Wot, bo, out, 4096, 4096);
}